// Round 1
// baseline (192.398 us; speedup 1.0000x reference)
//
#include <hip/hip_runtime.h>

typedef __bf16 bf16x8 __attribute__((ext_vector_type(8)));
typedef float  f32x4  __attribute__((ext_vector_type(4)));

#define ND   64
#define HD   128
#define NSEG 1024
#define ROWS_PER_BLOCK 512

__device__ __forceinline__ int lower_bound_i(const int* __restrict__ a, int n, int v) {
  int lo = 0, hi = n;
  while (lo < hi) { int m = (lo + hi) >> 1; if (a[m] < v) lo = m + 1; else hi = m; }
  return lo;
}

// K0: zero the segment-sum table, compute per-segment counts (x_batch is sorted)
__global__ __launch_bounds__(128) void k_init(const int* __restrict__ xb, int n,
                                              float* __restrict__ sums,
                                              float* __restrict__ counts) {
  const int s = blockIdx.x;
  sums[s * HD + threadIdx.x] = 0.f;
  if (threadIdx.x == 0) {
    int lo = lower_bound_i(xb, n, s);
    int hi = lower_bound_i(xb, n, s + 1);
    counts[s] = (float)(hi - lo);
  }
}

__device__ __forceinline__ void flush_seg(float* __restrict__ sums, int seg,
                                          float* seg_acc, int lane) {
  // seg_acc layout: lane holds (col = lane&15, rowgroup = lane>>4) partials per col-tile.
  // Reduce across the 4 rowgroups (lanes l, l^16, l^32, l^48), then lanes 0-15 emit atomics.
  #pragma unroll
  for (int ct = 0; ct < 8; ++ct) {
    float v = seg_acc[ct];
    v += __shfl_xor(v, 16);
    v += __shfl_xor(v, 32);
    if (lane < 16) atomicAdd(&sums[seg * HD + ct * 16 + lane], v);
  }
}

// K1: a = relu(x @ W1 + b1), segment-summed into sums[1024][128].
// Wave-level: 16 rows/tile, full 128 cols, K=64 via 2x mfma_f32_16x16x32_bf16 per col-tile.
// A frag: lane holds row (lane&15), k = 8*(lane>>4)+e. B frag: col (lane&15), same k map.
// (Same (lgrp,e)->k map on A and B => correct for any true hardware k-order.)
// D frag (HW-verified m89): col = lane&15, row = 4*(lane>>4)+reg.
__global__ __launch_bounds__(256) void k_phi(const float* __restrict__ x,
                                             const int* __restrict__ xb,
                                             const float* __restrict__ W1,
                                             const float* __restrict__ b1,
                                             float* __restrict__ sums, int n) {
  const int lane = threadIdx.x & 63;
  const int wave = threadIdx.x >> 6;
  const int l16  = lane & 15;
  const int lgrp = lane >> 4;

  // W1 fragments, held in registers for the whole block (gather once, L2-hot)
  bf16x8 bfrag[2][8];
  #pragma unroll
  for (int kt = 0; kt < 2; ++kt)
    #pragma unroll
    for (int ct = 0; ct < 8; ++ct) {
      bf16x8 f;
      #pragma unroll
      for (int e = 0; e < 8; ++e)
        f[e] = (__bf16)W1[(kt * 32 + lgrp * 8 + e) * HD + ct * 16 + l16];
      bfrag[kt][ct] = f;
    }

  float b1v[8];
  #pragma unroll
  for (int ct = 0; ct < 8; ++ct) b1v[ct] = b1[ct * 16 + l16];

  const int row0 = blockIdx.x * ROWS_PER_BLOCK;
  float seg_acc[8] = {0.f, 0.f, 0.f, 0.f, 0.f, 0.f, 0.f, 0.f};
  int seg_cur = -1;

  for (int chunk = 0; chunk < ROWS_PER_BLOCK; chunk += 64) {
    if (row0 + chunk >= n) break;      // n % 64 == 0 -> all tiles full
    const int rb = row0 + chunk + wave * 16;

    int sb = xb[rb + l16];             // segment of each of the 16 rows
    int sfirst = __builtin_amdgcn_readfirstlane(sb);
    const bool uni = (__all(sb == sfirst) != 0);

    // x tile: 32 contiguous bytes per lane, wave covers 16 full rows per k-tile
    const float* xr = x + (size_t)(rb + l16) * ND + lgrp * 8;
    f32x4 v0 = *(const f32x4*)(xr);
    f32x4 v1 = *(const f32x4*)(xr + 4);
    f32x4 v2 = *(const f32x4*)(xr + 32);
    f32x4 v3 = *(const f32x4*)(xr + 36);
    bf16x8 a0, a1;
    #pragma unroll
    for (int e = 0; e < 4; ++e) {
      a0[e]     = (__bf16)v0[e];
      a0[e + 4] = (__bf16)v1[e];
      a1[e]     = (__bf16)v2[e];
      a1[e + 4] = (__bf16)v3[e];
    }

    f32x4 acc[8];
    #pragma unroll
    for (int ct = 0; ct < 8; ++ct) {
      f32x4 c; c[0] = c[1] = c[2] = c[3] = b1v[ct];   // bias broadcast (all rows, same col)
      acc[ct] = c;
    }
    #pragma unroll
    for (int ct = 0; ct < 8; ++ct) {
      acc[ct] = __builtin_amdgcn_mfma_f32_16x16x32_bf16(a0, bfrag[0][ct], acc[ct], 0, 0, 0);
      acc[ct] = __builtin_amdgcn_mfma_f32_16x16x32_bf16(a1, bfrag[1][ct], acc[ct], 0, 0, 0);
    }

    float r[8][4];
    #pragma unroll
    for (int ct = 0; ct < 8; ++ct)
      #pragma unroll
      for (int i = 0; i < 4; ++i) r[ct][i] = fmaxf(acc[ct][i], 0.f);

    if (uni) {
      if (sfirst != seg_cur) {
        if (seg_cur >= 0) flush_seg(sums, seg_cur, seg_acc, lane);
        #pragma unroll
        for (int ct = 0; ct < 8; ++ct) seg_acc[ct] = 0.f;
        seg_cur = sfirst;
      }
      #pragma unroll
      for (int ct = 0; ct < 8; ++ct)
        seg_acc[ct] += (r[ct][0] + r[ct][1]) + (r[ct][2] + r[ct][3]);
    } else {
      // rare boundary tile (~1k of 125k): flush, then per-row atomics
      if (seg_cur >= 0) flush_seg(sums, seg_cur, seg_acc, lane);
      #pragma unroll
      for (int ct = 0; ct < 8; ++ct) seg_acc[ct] = 0.f;
      const int rrow = rb + lgrp * 4;  // D-layout rows owned by this lane
      const int s0 = xb[rrow], s1 = xb[rrow + 1], s2 = xb[rrow + 2], s3 = xb[rrow + 3];
      #pragma unroll
      for (int ct = 0; ct < 8; ++ct) {
        atomicAdd(&sums[s0 * HD + ct * 16 + l16], r[ct][0]);
        atomicAdd(&sums[s1 * HD + ct * 16 + l16], r[ct][1]);
        atomicAdd(&sums[s2 * HD + ct * 16 + l16], r[ct][2]);
        atomicAdd(&sums[s3 * HD + ct * 16 + l16], r[ct][3]);
      }
      seg_cur = __shfl(sb, 15);        // continue accumulating for last row's segment
    }
  }
  if (seg_cur >= 0) flush_seg(sums, seg_cur, seg_acc, lane);
}

// K2: per segment: mean -> @W2+b2 (deferred) -> relu(@W3+b3) -> @W4+b4
__global__ __launch_bounds__(128) void k_rho(const float* __restrict__ sums,
                                             const float* __restrict__ counts,
                                             const float* __restrict__ W2, const float* __restrict__ b2,
                                             const float* __restrict__ W3, const float* __restrict__ b3,
                                             const float* __restrict__ W4, const float* __restrict__ b4,
                                             float* __restrict__ out) {
  const int s = blockIdx.x;
  const int j = threadIdx.x;
  __shared__ float bufA[HD];
  __shared__ float bufB[HD];

  const float c = counts[s];
  const float inv = 1.f / fmaxf(c, 1.f);
  bufA[j] = sums[s * HD + j] * inv;          // mean of relu-activations
  __syncthreads();

  float hid = b2[j];
  #pragma unroll 4
  for (int k = 0; k < HD; ++k) hid = fmaf(bufA[k], W2[k * HD + j], hid);
  if (c == 0.f) hid = 0.f;                    // reference: empty segment -> hid = 0 (not b2)
  bufB[j] = hid;
  __syncthreads();

  float t = b3[j];
  #pragma unroll 4
  for (int k = 0; k < HD; ++k) t = fmaf(bufB[k], W3[k * HD + j], t);
  t = fmaxf(t, 0.f);
  bufA[j] = t;                                // safe: all bufA reads completed at prior barrier
  __syncthreads();

  if (j < 16) {
    float o = b4[j];
    #pragma unroll 4
    for (int k = 0; k < HD; ++k) o = fmaf(bufA[k], W4[k * 16 + j], o);
    out[s * 16 + j] = o;
  }
}

extern "C" void kernel_launch(void* const* d_in, const int* in_sizes, int n_in,
                              void* d_out, int out_size, void* d_ws, size_t ws_size,
                              hipStream_t stream) {
  const float* x  = (const float*)d_in[0];
  const int*   xb = (const int*)  d_in[1];
  const float* W1 = (const float*)d_in[2];
  const float* b1 = (const float*)d_in[3];
  const float* W2 = (const float*)d_in[4];
  const float* b2 = (const float*)d_in[5];
  const float* W3 = (const float*)d_in[6];
  const float* b3 = (const float*)d_in[7];
  const float* W4 = (const float*)d_in[8];
  const float* b4 = (const float*)d_in[9];
  float* out = (float*)d_out;
  const int n = in_sizes[1];                 // number of nodes (x_batch length)

  float* sums   = (float*)d_ws;              // [NSEG][HD]
  float* counts = sums + (size_t)NSEG * HD;  // [NSEG]

  k_init<<<NSEG, 128, 0, stream>>>(xb, n, sums, counts);
  const int nblocks = (n + ROWS_PER_BLOCK - 1) / ROWS_PER_BLOCK;
  k_phi<<<nblocks, 256, 0, stream>>>(x, xb, W1, b1, sums, n);
  k_rho<<<NSEG, 128, 0, stream>>>(sums, counts, W2, b2, W3, b3, W4, b4, out);
}

// Round 2
// 157.107 us; speedup vs baseline: 1.2246x; 1.2246x over previous
//
#include <hip/hip_runtime.h>

typedef __bf16 bf16x8 __attribute__((ext_vector_type(8)));
typedef float  f32x4  __attribute__((ext_vector_type(4)));

#define ND   64
#define HD   128
#define NSEG 1024
#define ROWS_PER_BLOCK 512

__device__ __forceinline__ int lower_bound_i(const int* __restrict__ a, int n, int v) {
  int lo = 0, hi = n;
  while (lo < hi) { int m = (lo + hi) >> 1; if (a[m] < v) lo = m + 1; else hi = m; }
  return lo;
}

// K0: zero the segment-sum table, compute per-segment counts (x_batch is sorted)
__global__ __launch_bounds__(128) void k_init(const int* __restrict__ xb, int n,
                                              float* __restrict__ sums,
                                              float* __restrict__ counts) {
  const int s = blockIdx.x;
  sums[s * HD + threadIdx.x] = 0.f;
  if (threadIdx.x == 0) {
    int lo = lower_bound_i(xb, n, s);
    int hi = lower_bound_i(xb, n, s + 1);
    counts[s] = (float)(hi - lo);
  }
}

__device__ __forceinline__ void flush_seg(float* __restrict__ sums, int seg,
                                          float* seg_acc, int lane) {
  // lane holds (col = lane&15, rowgroup = lane>>4) partials per col-tile.
  #pragma unroll
  for (int ct = 0; ct < 8; ++ct) {
    float v = seg_acc[ct];
    v += __shfl_xor(v, 16);
    v += __shfl_xor(v, 32);
    if (lane < 16) atomicAdd(&sums[seg * HD + ct * 16 + lane], v);
  }
}

// K1: segment-sum of relu(x @ W1 + b1) into sums[1024][128].
// W1 fragments live in LDS (16 KB), re-read each tile -> VGPRs ~110 -> 4 waves/SIMD.
// Depth-1 software pipeline on the x tile loads.
// A frag: lane holds row (lane&15), k = 32*kt + 8*(lane>>4)+e. B frag: col (lane&15),
// same k map (same map on A and B => correct for any true hardware k-order).
// D frag (HW-verified m89): col = lane&15, row = 4*(lane>>4)+reg.
__global__ __launch_bounds__(256, 4) void k_phi(const float* __restrict__ x,
                                                const int* __restrict__ xb,
                                                const float* __restrict__ W1,
                                                const float* __restrict__ b1,
                                                float* __restrict__ sums, int n) {
  __shared__ __align__(16) char ldsW[16 * 1024];
  const int lane = threadIdx.x & 63;
  const int wave = threadIdx.x >> 6;
  const int l16  = lane & 15;
  const int lgrp = lane >> 4;

  // Stage W1 fragments: frag f = kt*8+ct, stored [f][lane][16B]. Wave w builds 4 frags.
  #pragma unroll
  for (int i = 0; i < 4; ++i) {
    const int f  = wave + i * 4;
    const int kt = f >> 3, ct = f & 7;
    bf16x8 fr;
    #pragma unroll
    for (int e = 0; e < 8; ++e)
      fr[e] = (__bf16)W1[(kt * 32 + lgrp * 8 + e) * HD + ct * 16 + l16];
    *(bf16x8*)(&ldsW[f * 1024 + lane * 16]) = fr;
  }
  float b1v[8];
  #pragma unroll
  for (int ct = 0; ct < 8; ++ct) b1v[ct] = b1[ct * 16 + l16];
  __syncthreads();

  const int row0 = blockIdx.x * ROWS_PER_BLOCK;
  if (row0 >= n) return;                       // whole block exits together (barrier-safe)
  const int iters = min(ROWS_PER_BLOCK, n - row0) >> 6;   // n % 64 == 0

  const int    myrow = row0 + wave * 16 + l16;
  const float* xp    = x + (size_t)myrow * ND + lgrp * 8;
  const int*   xbp   = xb + myrow;

  float seg_acc[8] = {0.f, 0.f, 0.f, 0.f, 0.f, 0.f, 0.f, 0.f};
  int   seg_cur = -1;

  // prologue: tile 0 in flight
  f32x4 v0 = *(const f32x4*)(xp);
  f32x4 v1 = *(const f32x4*)(xp + 4);
  f32x4 v2 = *(const f32x4*)(xp + 32);
  f32x4 v3 = *(const f32x4*)(xp + 36);
  int   sb = *xbp;

#define COMPUTE(IT)                                                                   \
  {                                                                                   \
    int sfirst = __builtin_amdgcn_readfirstlane(sb);                                  \
    const bool uni = (__all(sb == sfirst) != 0);                                      \
    bf16x8 a0, a1;                                                                    \
    _Pragma("unroll")                                                                 \
    for (int e = 0; e < 4; ++e) {                                                     \
      a0[e] = (__bf16)v0[e]; a0[e + 4] = (__bf16)v1[e];                               \
      a1[e] = (__bf16)v2[e]; a1[e + 4] = (__bf16)v3[e];                               \
    }                                                                                 \
    int lb = lane * 16;                                                               \
    asm volatile("" : "+v"(lb));  /* defeat LICM: keep frag reads inside the loop */  \
    f32x4 acc[8];                                                                     \
    _Pragma("unroll")                                                                 \
    for (int ct = 0; ct < 8; ++ct) {                                                  \
      f32x4 c; c[0] = c[1] = c[2] = c[3] = b1v[ct];                                   \
      bf16x8 f0 = *(const bf16x8*)(&ldsW[ct * 1024 + lb]);                            \
      bf16x8 f1 = *(const bf16x8*)(&ldsW[(8 + ct) * 1024 + lb]);                      \
      c = __builtin_amdgcn_mfma_f32_16x16x32_bf16(a0, f0, c, 0, 0, 0);                \
      acc[ct] = __builtin_amdgcn_mfma_f32_16x16x32_bf16(a1, f1, c, 0, 0, 0);          \
    }                                                                                 \
    if (uni) {                                                                        \
      if (sfirst != seg_cur) {                                                        \
        if (seg_cur >= 0) flush_seg(sums, seg_cur, seg_acc, lane);                    \
        _Pragma("unroll")                                                             \
        for (int ct = 0; ct < 8; ++ct) seg_acc[ct] = 0.f;                             \
        seg_cur = sfirst;                                                             \
      }                                                                               \
      _Pragma("unroll")                                                               \
      for (int ct = 0; ct < 8; ++ct)                                                  \
        seg_acc[ct] += (fmaxf(acc[ct][0], 0.f) + fmaxf(acc[ct][1], 0.f)) +            \
                       (fmaxf(acc[ct][2], 0.f) + fmaxf(acc[ct][3], 0.f));             \
    } else {                                                                          \
      if (seg_cur >= 0) flush_seg(sums, seg_cur, seg_acc, lane);                      \
      _Pragma("unroll")                                                               \
      for (int ct = 0; ct < 8; ++ct) seg_acc[ct] = 0.f;                               \
      const int* xq = xb + row0 + (IT) * 64 + wave * 16 + lgrp * 4;                   \
      const int s0 = xq[0], s1 = xq[1], s2 = xq[2], s3 = xq[3];                       \
      _Pragma("unroll")                                                               \
      for (int ct = 0; ct < 8; ++ct) {                                                \
        atomicAdd(&sums[s0 * HD + ct * 16 + l16], fmaxf(acc[ct][0], 0.f));            \
        atomicAdd(&sums[s1 * HD + ct * 16 + l16], fmaxf(acc[ct][1], 0.f));            \
        atomicAdd(&sums[s2 * HD + ct * 16 + l16], fmaxf(acc[ct][2], 0.f));            \
        atomicAdd(&sums[s3 * HD + ct * 16 + l16], fmaxf(acc[ct][3], 0.f));            \
      }                                                                               \
      seg_cur = __shfl(sb, 15);                                                       \
    }                                                                                 \
  }

  for (int it = 0; it < iters - 1; ++it) {
    const float* xn = xp + (size_t)(it + 1) * (64 * ND);
    f32x4 w0 = *(const f32x4*)(xn);          // prefetch next tile: in flight
    f32x4 w1 = *(const f32x4*)(xn + 4);      // under this tile's compute
    f32x4 w2 = *(const f32x4*)(xn + 32);
    f32x4 w3 = *(const f32x4*)(xn + 36);
    int   sbn = xbp[(it + 1) * 64];
    COMPUTE(it);
    v0 = w0; v1 = w1; v2 = w2; v3 = w3; sb = sbn;
  }
  COMPUTE(iters - 1);
#undef COMPUTE

  if (seg_cur >= 0) flush_seg(sums, seg_cur, seg_acc, lane);
}

// K2: per segment: mean -> @W2+b2 (deferred past the mean) -> relu(@W3+b3) -> @W4+b4
__global__ __launch_bounds__(128) void k_rho(const float* __restrict__ sums,
                                             const float* __restrict__ counts,
                                             const float* __restrict__ W2, const float* __restrict__ b2,
                                             const float* __restrict__ W3, const float* __restrict__ b3,
                                             const float* __restrict__ W4, const float* __restrict__ b4,
                                             float* __restrict__ out) {
  const int s = blockIdx.x;
  const int j = threadIdx.x;
  __shared__ float bufA[HD];
  __shared__ float bufB[HD];

  const float c = counts[s];
  const float inv = 1.f / fmaxf(c, 1.f);
  bufA[j] = sums[s * HD + j] * inv;
  __syncthreads();

  float hid = b2[j];
  #pragma unroll 4
  for (int k = 0; k < HD; ++k) hid = fmaf(bufA[k], W2[k * HD + j], hid);
  if (c == 0.f) hid = 0.f;                    // reference: empty segment -> hid = 0
  bufB[j] = hid;
  __syncthreads();

  float t = b3[j];
  #pragma unroll 4
  for (int k = 0; k < HD; ++k) t = fmaf(bufB[k], W3[k * HD + j], t);
  t = fmaxf(t, 0.f);
  bufA[j] = t;
  __syncthreads();

  if (j < 16) {
    float o = b4[j];
    #pragma unroll 4
    for (int k = 0; k < HD; ++k) o = fmaf(bufA[k], W4[k * 16 + j], o);
    out[s * 16 + j] = o;
  }
}

extern "C" void kernel_launch(void* const* d_in, const int* in_sizes, int n_in,
                              void* d_out, int out_size, void* d_ws, size_t ws_size,
                              hipStream_t stream) {
  const float* x  = (const float*)d_in[0];
  const int*   xb = (const int*)  d_in[1];
  const float* W1 = (const float*)d_in[2];
  const float* b1 = (const float*)d_in[3];
  const float* W2 = (const float*)d_in[4];
  const float* b2 = (const float*)d_in[5];
  const float* W3 = (const float*)d_in[6];
  const float* b3 = (const float*)d_in[7];
  const float* W4 = (const float*)d_in[8];
  const float* b4 = (const float*)d_in[9];
  float* out = (float*)d_out;
  const int n = in_sizes[1];

  float* sums   = (float*)d_ws;              // [NSEG][HD]
  float* counts = sums + (size_t)NSEG * HD;  // [NSEG]

  k_init<<<NSEG, 128, 0, stream>>>(xb, n, sums, counts);
  const int nblocks = (n + ROWS_PER_BLOCK - 1) / ROWS_PER_BLOCK;
  k_phi<<<nblocks, 256, 0, stream>>>(x, xb, W1, b1, sums, n);
  k_rho<<<NSEG, 128, 0, stream>>>(sums, counts, W2, b2, W3, b3, W4, b4, out);
}